// Round 1
// baseline (388.427 us; speedup 1.0000x reference)
//
#include <hip/hip_runtime.h>
#include <hip/hip_fp16.h>

#define BATCH 4096
#define EPS 1e-5f

typedef __half h16;

__device__ __forceinline__ float tanh_fast(float x){
  float e = __expf(2.0f*x);
  return 1.0f - 2.0f*__builtin_amdgcn_rcpf(e + 1.0f);
}

// ---------------- transpose: ms[4096][6000] f32 -> msT[6000][4096] f16 ----------------
__global__ __launch_bounds__(256) void k_transpose(const float* __restrict__ ms, h16* __restrict__ msT){
  __shared__ float tile[64][65];
  int tc = blockIdx.x * 64;            // column tile (N dim, 6000)
  int tb = blockIdx.y * 64;            // batch tile
  int tx = threadIdx.x & 63;
  int ty = threadIdx.x >> 6;
  #pragma unroll
  for (int k=0;k<16;++k){
    int r = ty + k*4;                  // b offset in tile
    int c = tc + tx;
    if (c < 6000) tile[r][tx] = ms[(size_t)(tb + r)*6000 + c];
  }
  __syncthreads();
  #pragma unroll
  for (int k=0;k<16;++k){
    int r = ty + k*4;                  // c offset in tile
    int c = tc + r;
    if (c < 6000) msT[(size_t)c*BATCH + tb + tx] = __float2half(tile[tx][r]);
  }
}

// ---------------- level 1: gather + linear(16->20) + tanh; stats ----------------
__global__ __launch_bounds__(256) void k_l1(const h16* __restrict__ msT, const int* __restrict__ gidx,
    const float* __restrict__ W1, const float* __restrict__ b1,
    h16* __restrict__ H1, float* __restrict__ stats1){
  const int s = blockIdx.x;
  const int tid = threadIdx.x;
  __shared__ int isr[16];
  __shared__ float red[8][20];
  if (tid < 16) isr[tid] = gidx[s*16 + tid] * BATCH;
  __syncthreads();
  int base[16];
  #pragma unroll
  for (int g=0;g<16;++g) base[g] = isr[g];
  const float* Wp = W1 + s*320;
  const float* bp = b1 + s*20;
  float sum[20], sq[20];
  #pragma unroll
  for (int o=0;o<20;++o){ sum[o]=0.f; sq[o]=0.f; }
  for (int it=0; it<16; ++it){
    int b = it*256 + tid;
    float x[16];
    #pragma unroll
    for (int g=0;g<16;++g) x[g] = __half2float(msT[base[g] + b]);
    #pragma unroll
    for (int o=0;o<20;++o){
      float h = bp[o];
      #pragma unroll
      for (int g=0;g<16;++g) h = fmaf(x[g], Wp[o*16+g], h);
      h = tanh_fast(h);
      H1[(s*20+o)*BATCH + b] = __float2half(h);
      sum[o] += h; sq[o] = fmaf(h,h,sq[o]);
    }
  }
  int lane = tid & 63, wv = tid >> 6;
  #pragma unroll
  for (int o=0;o<20;++o){
    float S = sum[o], Q = sq[o];
    #pragma unroll
    for (int off=32; off>0; off>>=1){ S += __shfl_xor(S, off); Q += __shfl_xor(Q, off); }
    if (lane==0){ red[wv*2][o] = S; red[wv*2+1][o] = Q; }
  }
  __syncthreads();
  if (tid < 20){
    float S=0.f, Q=0.f;
    #pragma unroll
    for (int w=0;w<4;++w){ S += red[w*2][tid]; Q += red[w*2+1][tid]; }
    stats1[(s*20+tid)*2]   = S;
    stats1[(s*20+tid)*2+1] = Q;
  }
}

// ---------------- fold BN of previous level into next level's weights ----------------
// part layout: part[(ch*2 + {0,1})*NBC + bc] ; ch = p*NCH + t (flat channel of prev level)
template<int NCH, int NJ, int NBC>
__global__ __launch_bounds__(256) void k_fold(const float* __restrict__ W, const float* __restrict__ bb,
    const float* __restrict__ g, const float* __restrict__ beta,
    const float* __restrict__ part, float* __restrict__ Wf, float* __restrict__ bf){
  const int p = blockIdx.x;
  const int tid = threadIdx.x;
  __shared__ float aL[NCH], cL[NCH];
  for (int t = tid; t < NCH; t += 256){
    int ch = p*NCH + t;
    float S=0.f, Q=0.f;
    for (int bc=0; bc<NBC; ++bc){ S += part[(ch*2)*NBC + bc]; Q += part[(ch*2+1)*NBC + bc]; }
    float mu  = S * (1.0f/BATCH);
    float var = Q * (1.0f/BATCH) - mu*mu;
    float a = g[ch] * rsqrtf(var + EPS);
    aL[t] = a;
    cL[t] = beta[ch] - a*mu;
  }
  __syncthreads();
  const int NW = NCH*NJ;
  for (int e = tid; e < NW; e += 256){
    int i = e % NCH;
    Wf[p*NW + e] = W[p*NW + e] * aL[i];
  }
  if (tid < NJ){
    float sv = bb[p*NJ + tid];
    for (int i=0;i<NCH;++i) sv = fmaf(W[p*NW + tid*NCH + i], cL[i], sv);
    bf[p*NJ + tid] = sv;
  }
}

// ---------------- generic mid level: linear(NIN->NJ)+tanh from folded weights ----------------
template<int NIN, int NJ, int NBC>
__global__ __launch_bounds__(256) void k_level(const h16* __restrict__ Hin, const float* __restrict__ Wf,
    const float* __restrict__ bf, h16* __restrict__ Hout, float* __restrict__ part){
  const int bc = blockIdx.x;
  const int p  = blockIdx.y;
  const int tid = threadIdx.x;
  constexpr int BPT = BATCH / (NBC*256);
  __shared__ float red[8][NJ];
  const float* Wp = Wf + p*NIN*NJ;
  float sum[NJ], sq[NJ];
  #pragma unroll
  for (int j=0;j<NJ;++j){ sum[j]=0.f; sq[j]=0.f; }
  for (int ib=0; ib<BPT; ++ib){
    int b = bc*(256*BPT) + ib*256 + tid;
    float acc[NJ];
    #pragma unroll
    for (int j=0;j<NJ;++j) acc[j] = bf[p*NJ + j];
    for (int i0=0; i0<NIN; i0+=4){
      float x[4];
      #pragma unroll
      for (int k=0;k<4;++k) x[k] = __half2float(Hin[(p*NIN + i0 + k)*BATCH + b]);
      #pragma unroll
      for (int j=0;j<NJ;++j){
        #pragma unroll
        for (int k=0;k<4;++k) acc[j] = fmaf(x[k], Wp[j*NIN + i0 + k], acc[j]);
      }
    }
    #pragma unroll
    for (int j=0;j<NJ;++j){
      float h = tanh_fast(acc[j]);
      Hout[(p*NJ + j)*BATCH + b] = __float2half(h);
      sum[j] += h; sq[j] = fmaf(h,h,sq[j]);
    }
  }
  int lane = tid & 63, wv = tid >> 6;
  #pragma unroll
  for (int j=0;j<NJ;++j){
    float S = sum[j], Q = sq[j];
    #pragma unroll
    for (int off=32; off>0; off>>=1){ S += __shfl_xor(S, off); Q += __shfl_xor(Q, off); }
    if (lane==0){ red[wv*2][j] = S; red[wv*2+1][j] = Q; }
  }
  __syncthreads();
  if (tid < NJ){
    float S=0.f, Q=0.f;
    #pragma unroll
    for (int w=0;w<4;++w){ S += red[w*2][tid]; Q += red[w*2+1][tid]; }
    part[((p*NJ + tid)*2  )*NBC + bc] = S;
    part[((p*NJ + tid)*2+1)*NBC + bc] = Q;
  }
}

// ---------------- root: linear(256->64)+tanh ----------------
__global__ __launch_bounds__(64) void k_root(const h16* __restrict__ H3, const float* __restrict__ Wrf,
    const float* __restrict__ brf, h16* __restrict__ Hr, float* __restrict__ partR){
  const int bc = blockIdx.x;   // 64
  const int oc = blockIdx.y;   // 4
  const int tid = threadIdx.x; // 64
  const int b = bc*64 + tid;
  const int ob = oc*16;
  float acc[16];
  #pragma unroll
  for (int j=0;j<16;++j) acc[j] = brf[ob + j];
  for (int i0=0; i0<256; i0+=4){
    float x[4];
    #pragma unroll
    for (int k=0;k<4;++k) x[k] = __half2float(H3[(i0+k)*BATCH + b]);
    #pragma unroll
    for (int j=0;j<16;++j){
      #pragma unroll
      for (int k=0;k<4;++k) acc[j] = fmaf(x[k], Wrf[(ob+j)*256 + i0 + k], acc[j]);
    }
  }
  #pragma unroll
  for (int j=0;j<16;++j){
    float h = tanh_fast(acc[j]);
    Hr[b*64 + ob + j] = __float2half(h);
    float S = h, Q = h*h;
    #pragma unroll
    for (int off=32; off>0; off>>=1){ S += __shfl_xor(S, off); Q += __shfl_xor(Q, off); }
    if (tid==0){ partR[((ob+j)*2)*64 + bc] = S; partR[((ob+j)*2+1)*64 + bc] = Q; }
  }
}

// ---------------- final BN on root output ----------------
__global__ __launch_bounds__(256) void k_final(const h16* __restrict__ Hr, const float* __restrict__ partR,
    const float* __restrict__ gr, const float* __restrict__ betar, float* __restrict__ out){
  __shared__ float aL[64], cL[64];
  const int tid = threadIdx.x;
  if (tid < 64){
    float S=0.f, Q=0.f;
    for (int bc=0; bc<64; ++bc){ S += partR[(tid*2)*64 + bc]; Q += partR[(tid*2+1)*64 + bc]; }
    float mu  = S * (1.0f/BATCH);
    float var = Q * (1.0f/BATCH) - mu*mu;
    float a = gr[tid] * rsqrtf(var + EPS);
    aL[tid] = a; cL[tid] = betar[tid] - a*mu;
  }
  __syncthreads();
  const int base = blockIdx.x * 4096;
  #pragma unroll
  for (int k=0;k<16;++k){
    int e = base + k*256 + tid;
    int o = e & 63;
    out[e] = aL[o]*__half2float(Hr[e]) + cL[o];
  }
}

extern "C" void kernel_launch(void* const* d_in, const int* in_sizes, int n_in,
                              void* d_out, int out_size, void* d_ws, size_t ws_size,
                              hipStream_t stream) {
  const float* ms    = (const float*)d_in[0];
  const int*   gidx  = (const int*)  d_in[1];
  const float* W1    = (const float*)d_in[2];
  const float* b1    = (const float*)d_in[3];
  const float* g1    = (const float*)d_in[4];
  const float* beta1 = (const float*)d_in[5];
  const float* W2    = (const float*)d_in[6];
  const float* b2    = (const float*)d_in[7];
  const float* g2    = (const float*)d_in[8];
  const float* beta2 = (const float*)d_in[9];
  const float* W3    = (const float*)d_in[10];
  const float* b3    = (const float*)d_in[11];
  const float* g3    = (const float*)d_in[12];
  const float* beta3 = (const float*)d_in[13];
  const float* Wr    = (const float*)d_in[14];
  const float* br    = (const float*)d_in[15];
  const float* gr    = (const float*)d_in[16];
  const float* betar = (const float*)d_in[17];
  float* out = (float*)d_out;

  char* w = (char*)d_ws;
  size_t off = 0;
  auto take = [&](size_t bytes)->char*{
    char* p = w + off;
    off = (off + bytes + 255) & ~(size_t)255;
    return p;
  };
  h16*   msT    = (h16*)  take((size_t)6000*BATCH*2);
  h16*   H1     = (h16*)  take((size_t)10240*BATCH*2);
  h16*   H2     = (h16*)  take((size_t)1536*BATCH*2);
  h16*   H3     = (h16*)  take((size_t)256*BATCH*2);
  h16*   Hr     = (h16*)  take((size_t)BATCH*64*2);
  float* stats1 = (float*)take((size_t)10240*2*4);
  float* part2  = (float*)take((size_t)1536*2*8*4);
  float* part3  = (float*)take((size_t)256*2*16*4);
  float* partR  = (float*)take((size_t)64*2*64*4);
  float* W2f    = (float*)take((size_t)64*24*160*4);
  float* b2f    = (float*)take((size_t)64*24*4);
  float* W3f    = (float*)take((size_t)8*32*192*4);
  float* b3f    = (float*)take((size_t)8*32*4);
  float* Wrf    = (float*)take((size_t)64*256*4);
  float* brf    = (float*)take((size_t)64*4);
  if (off > ws_size) return;  // workspace too small -> fail validation loudly

  k_transpose<<<dim3(94,64), 256, 0, stream>>>(ms, msT);
  k_l1<<<512, 256, 0, stream>>>(msT, gidx, W1, b1, H1, stats1);
  k_fold<160,24,1><<<64, 256, 0, stream>>>(W2, b2, g1, beta1, stats1, W2f, b2f);
  k_level<160,24,8><<<dim3(8,64), 256, 0, stream>>>(H1, W2f, b2f, H2, part2);
  k_fold<192,32,8><<<8, 256, 0, stream>>>(W3, b3, g2, beta2, part2, W3f, b3f);
  k_level<192,32,16><<<dim3(16,8), 256, 0, stream>>>(H2, W3f, b3f, H3, part3);
  k_fold<256,64,16><<<1, 256, 0, stream>>>(Wr, br, g3, beta3, part3, Wrf, brf);
  k_root<<<dim3(64,4), 64, 0, stream>>>(H3, Wrf, brf, Hr, partR);
  k_final<<<64, 256, 0, stream>>>(Hr, partR, gr, betar, out);
}

// Round 2
// 290.071 us; speedup vs baseline: 1.3391x; 1.3391x over previous
//
#include <hip/hip_runtime.h>
#include <hip/hip_fp16.h>

#define BATCH 4096
#define EPS 1e-5f

typedef __half h16;

union H8 { float4 f4; h16 h[8]; };
union H4 { float2 f2; h16 h[4]; };
union H2U { float f; __half2 h2; unsigned int u; };

__device__ __forceinline__ float tanh_fast(float x){
  float e = __expf(2.0f*x);
  return 1.0f - 2.0f*__builtin_amdgcn_rcpf(e + 1.0f);
}

__device__ __forceinline__ float wred(float v){
  #pragma unroll
  for (int off=32; off; off>>=1) v += __shfl_xor(v, off);
  return v;
}

// ---------------- transpose: ms[4096][6000] f32 -> msT[6000][4096] f16 ----------------
__global__ __launch_bounds__(256) void k_transpose(const float* __restrict__ ms, h16* __restrict__ msT){
  __shared__ float tile[64][65];
  int tc = blockIdx.x * 64;            // column tile (N dim, 6000)
  int tb = blockIdx.y * 64;            // batch tile
  int tx = threadIdx.x & 63;
  int ty = threadIdx.x >> 6;
  #pragma unroll
  for (int k=0;k<16;++k){
    int r = ty + k*4;
    int c = tc + tx;
    if (c < 6000) tile[r][tx] = ms[(size_t)(tb + r)*6000 + c];
  }
  __syncthreads();
  #pragma unroll
  for (int k=0;k<16;++k){
    int r = ty + k*4;
    int c = tc + r;
    if (c < 6000) msT[(size_t)c*BATCH + tb + tx] = __float2half(tile[tx][r]);
  }
}

// ---------------- pass A: level-1 stats only (no H1 store) ----------------
// grid (16 bc, 512 s), block 64; thread handles 4 batch elems
__global__ __launch_bounds__(64) void k_statsA(const h16* __restrict__ msT, const int* __restrict__ gidx,
    const float* __restrict__ W1, const float* __restrict__ b1, float* __restrict__ part1){
  const int s = blockIdx.y;
  const int bc = blockIdx.x;           // 16
  const int lane = threadIdx.x;
  const int b0 = bc*256 + lane*4;
  const float* Wp = W1 + s*320;
  float acc[20][4];
  #pragma unroll
  for (int o=0;o<20;++o){
    float bv = b1[s*20+o];
    acc[o][0]=bv; acc[o][1]=bv; acc[o][2]=bv; acc[o][3]=bv;
  }
  #pragma unroll 4
  for (int g=0; g<16; ++g){
    const int row = gidx[s*16+g]*BATCH;
    H4 u; u.f2 = *reinterpret_cast<const float2*>(msT + row + b0);
    float x0=__half2float(u.h[0]), x1=__half2float(u.h[1]);
    float x2=__half2float(u.h[2]), x3=__half2float(u.h[3]);
    #pragma unroll
    for (int o=0;o<20;++o){
      float wv = Wp[o*16+g];
      acc[o][0]=fmaf(x0,wv,acc[o][0]);
      acc[o][1]=fmaf(x1,wv,acc[o][1]);
      acc[o][2]=fmaf(x2,wv,acc[o][2]);
      acc[o][3]=fmaf(x3,wv,acc[o][3]);
    }
  }
  #pragma unroll
  for (int o=0;o<20;++o){
    float h0=tanh_fast(acc[o][0]), h1=tanh_fast(acc[o][1]);
    float h2=tanh_fast(acc[o][2]), h3=tanh_fast(acc[o][3]);
    float S = (h0+h1)+(h2+h3);
    float Q = (h0*h0+h1*h1)+(h2*h2+h3*h3);
    S = wred(S); Q = wred(Q);
    if (lane==0){
      part1[((s*20+o)*2  )*16 + bc] = S;
      part1[((s*20+o)*2+1)*16 + bc] = Q;
    }
  }
}

// ---------------- fold BN of previous level into next level's weights ----------------
// part layout: part[(ch*2 + {0,1})*NBC + bc]; ch = p*NCH + t
// TR=true emits Wf[p][i][j] (for scatter access), else Wf[p][j][i]
template<int NCH, int NJ, int NBC, bool TR>
__global__ __launch_bounds__(256) void k_fold(const float* __restrict__ W, const float* __restrict__ bb,
    const float* __restrict__ g, const float* __restrict__ beta,
    const float* __restrict__ part, float* __restrict__ Wf, float* __restrict__ bf){
  const int p = blockIdx.x;
  const int tid = threadIdx.x;
  __shared__ float aL[NCH], cL[NCH];
  for (int t = tid; t < NCH; t += 256){
    int ch = p*NCH + t;
    float S=0.f, Q=0.f;
    for (int bc=0; bc<NBC; ++bc){ S += part[(ch*2)*NBC + bc]; Q += part[(ch*2+1)*NBC + bc]; }
    float mu  = S * (1.0f/BATCH);
    float var = Q * (1.0f/BATCH) - mu*mu;
    float a = g[ch] * rsqrtf(var + EPS);
    aL[t] = a;
    cL[t] = beta[ch] - a*mu;
  }
  __syncthreads();
  const int NW = NCH*NJ;
  for (int e = tid; e < NW; e += 256){
    if (TR){
      int j = e % NJ, i = e / NJ;
      Wf[p*NW + e] = W[p*NW + j*NCH + i] * aL[i];
    } else {
      int i = e % NCH;
      Wf[p*NW + e] = W[p*NW + e] * aL[i];
    }
  }
  if (tid < NJ){
    float sv = bb[p*NJ + tid];
    for (int i=0;i<NCH;++i) sv = fmaf(W[p*NW + tid*NCH + i], cL[i], sv);
    bf[p*NJ + tid] = sv;
  }
}

// ---------------- pass B: recompute h1 + folded level-2 -> H2[p][b][24] + stats ----------------
// grid (32 bc, 64 p), block 64; thread handles 2 batch elems
__global__ __launch_bounds__(64) void k_passB(const h16* __restrict__ msT, const int* __restrict__ gidx,
    const float* __restrict__ W1, const float* __restrict__ b1,
    const float* __restrict__ W2f, const float* __restrict__ b2f,
    h16* __restrict__ H2, float* __restrict__ part2){
  const int p = blockIdx.y;
  const int bc = blockIdx.x;           // 32
  const int lane = threadIdx.x;
  const int b0 = bc*128 + lane*2;
  float acc[24][2];
  #pragma unroll
  for (int j=0;j<24;++j){ float bv = b2f[p*24+j]; acc[j][0]=bv; acc[j][1]=bv; }
  for (int c2=0;c2<8;++c2){
    const int s = p*8 + c2;
    const float* Wp = W1 + s*320;
    const float* bp = b1 + s*20;
    float x0[16], x1[16];
    #pragma unroll
    for (int g=0; g<16; ++g){
      const int row = gidx[s*16+g]*BATCH;
      H2U u; u.f = *reinterpret_cast<const float*>(msT + row + b0);
      x0[g] = __half2float(u.h2.x);
      x1[g] = __half2float(u.h2.y);
    }
    const float* w2 = W2f + p*3840 + c2*20*24;   // [i][j] layout
    #pragma unroll 2
    for (int o=0;o<20;++o){
      float p0 = bp[o], p1 = p0;
      #pragma unroll
      for (int g=0; g<16; ++g){
        float wv = Wp[o*16+g];
        p0 = fmaf(x0[g], wv, p0);
        p1 = fmaf(x1[g], wv, p1);
      }
      p0 = tanh_fast(p0); p1 = tanh_fast(p1);
      const float* wj = w2 + o*24;
      #pragma unroll
      for (int j=0;j<24;++j){
        float wv = wj[j];
        acc[j][0] = fmaf(p0, wv, acc[j][0]);
        acc[j][1] = fmaf(p1, wv, acc[j][1]);
      }
    }
  }
  #pragma unroll
  for (int j=0;j<24;++j){ acc[j][0]=tanh_fast(acc[j][0]); acc[j][1]=tanh_fast(acc[j][1]); }
  #pragma unroll
  for (int k=0;k<2;++k){
    unsigned int* dst = reinterpret_cast<unsigned int*>(H2 + ((size_t)p*BATCH + b0 + k)*24);
    #pragma unroll
    for (int j2=0;j2<12;++j2){
      H2U u; u.h2 = __halves2half2(__float2half(acc[2*j2][k]), __float2half(acc[2*j2+1][k]));
      dst[j2] = u.u;
    }
  }
  #pragma unroll
  for (int j=0;j<24;++j){
    float S = acc[j][0]+acc[j][1];
    float Q = acc[j][0]*acc[j][0] + acc[j][1]*acc[j][1];
    S = wred(S); Q = wred(Q);
    if (lane==0){
      part2[((p*24+j)*2  )*32 + bc] = S;
      part2[((p*24+j)*2+1)*32 + bc] = Q;
    }
  }
}

// ---------------- pass C: level 3 from H2 -> H3[b][256] + stats ----------------
// grid (32 bc, 8 q), block 256 (4 waves x 8 outputs); thread handles 2 batch elems
__global__ __launch_bounds__(256) void k_passC(const h16* __restrict__ H2, const float* __restrict__ W3f,
    const float* __restrict__ b3f, h16* __restrict__ H3, float* __restrict__ part3){
  const int q = blockIdx.y;
  const int bc = blockIdx.x;           // 32
  const int wv = threadIdx.x >> 6;
  const int lane = threadIdx.x & 63;
  const int jb = wv*8;
  const int b0 = bc*128 + lane*2;
  float acc[8][2];
  #pragma unroll
  for (int j=0;j<8;++j){ float bv = b3f[q*32+jb+j]; acc[j][0]=bv; acc[j][1]=bv; }
  const float* wq = W3f + q*6144;      // [j][i] layout
  for (int c2=0;c2<8;++c2){
    const h16* src = H2 + ((size_t)(q*8+c2)*BATCH + b0)*24;
    #pragma unroll
    for (int sl=0; sl<3; ++sl){
      H8 ua, ub;
      ua.f4 = *reinterpret_cast<const float4*>(src + sl*8);
      ub.f4 = *reinterpret_cast<const float4*>(src + 24 + sl*8);
      float xa[8], xb[8];
      #pragma unroll
      for (int i=0;i<8;++i){ xa[i]=__half2float(ua.h[i]); xb[i]=__half2float(ub.h[i]); }
      #pragma unroll
      for (int j=0;j<8;++j){
        const float* wr = wq + (jb+j)*192 + c2*24 + sl*8;
        #pragma unroll
        for (int i=0;i<8;++i){
          float w_ = wr[i];
          acc[j][0] = fmaf(xa[i], w_, acc[j][0]);
          acc[j][1] = fmaf(xb[i], w_, acc[j][1]);
        }
      }
    }
  }
  #pragma unroll
  for (int j=0;j<8;++j){ acc[j][0]=tanh_fast(acc[j][0]); acc[j][1]=tanh_fast(acc[j][1]); }
  #pragma unroll
  for (int k=0;k<2;++k){
    H8 u;
    #pragma unroll
    for (int j=0;j<8;++j) u.h[j] = __float2half(acc[j][k]);
    *reinterpret_cast<float4*>(H3 + (size_t)(b0+k)*256 + q*32 + jb) = u.f4;
  }
  #pragma unroll
  for (int j=0;j<8;++j){
    float S = acc[j][0]+acc[j][1];
    float Q = acc[j][0]*acc[j][0] + acc[j][1]*acc[j][1];
    S = wred(S); Q = wred(Q);
    if (lane==0){
      part3[((q*32+jb+j)*2  )*32 + bc] = S;
      part3[((q*32+jb+j)*2+1)*32 + bc] = Q;
    }
  }
}

// ---------------- pass D: root linear+tanh from H3 -> Hr f32 [b][64] + stats ----------------
// grid 64 bc, block 256 (4 waves x 16 outputs); thread handles 1 batch elem
__global__ __launch_bounds__(256) void k_passD(const h16* __restrict__ H3, const float* __restrict__ Wrf,
    const float* __restrict__ brf, float* __restrict__ Hr, float* __restrict__ partR){
  const int bc = blockIdx.x;           // 64
  const int wv = threadIdx.x >> 6;
  const int lane = threadIdx.x & 63;
  const int jb = wv*16;
  const int b = bc*64 + lane;
  float acc[16];
  #pragma unroll
  for (int j=0;j<16;++j) acc[j] = brf[jb+j];
  const h16* src = H3 + (size_t)b*256;
  #pragma unroll 2
  for (int sl=0; sl<32; ++sl){
    H8 u; u.f4 = *reinterpret_cast<const float4*>(src + sl*8);
    float xv[8];
    #pragma unroll
    for (int i=0;i<8;++i) xv[i]=__half2float(u.h[i]);
    #pragma unroll
    for (int j=0;j<16;++j){
      const float* wr = Wrf + (jb+j)*256 + sl*8;
      #pragma unroll
      for (int i=0;i<8;++i) acc[j] = fmaf(xv[i], wr[i], acc[j]);
    }
  }
  #pragma unroll
  for (int j=0;j<16;++j) acc[j] = tanh_fast(acc[j]);
  #pragma unroll
  for (int j4=0;j4<4;++j4){
    float4 v = make_float4(acc[j4*4],acc[j4*4+1],acc[j4*4+2],acc[j4*4+3]);
    *reinterpret_cast<float4*>(Hr + (size_t)b*64 + jb + j4*4) = v;
  }
  #pragma unroll
  for (int j=0;j<16;++j){
    float S = wred(acc[j]);
    float Q = wred(acc[j]*acc[j]);
    if (lane==0){
      partR[((jb+j)*2  )*64 + bc] = S;
      partR[((jb+j)*2+1)*64 + bc] = Q;
    }
  }
}

// ---------------- final BN on root output ----------------
__global__ __launch_bounds__(256) void k_final(const float* __restrict__ Hr, const float* __restrict__ partR,
    const float* __restrict__ gr, const float* __restrict__ betar, float* __restrict__ out){
  __shared__ float aL[64], cL[64];
  const int tid = threadIdx.x;
  if (tid < 64){
    float S=0.f, Q=0.f;
    for (int bc=0; bc<64; ++bc){ S += partR[(tid*2)*64 + bc]; Q += partR[(tid*2+1)*64 + bc]; }
    float mu  = S * (1.0f/BATCH);
    float var = Q * (1.0f/BATCH) - mu*mu;
    float a = gr[tid] * rsqrtf(var + EPS);
    aL[tid] = a; cL[tid] = betar[tid] - a*mu;
  }
  __syncthreads();
  const int base4 = blockIdx.x * 1024;
  #pragma unroll
  for (int k=0;k<4;++k){
    int i4 = base4 + k*256 + tid;
    float4 v = *reinterpret_cast<const float4*>(Hr + (size_t)i4*4);
    int o = (i4*4)&63;
    float4 r;
    r.x = aL[o  ]*v.x + cL[o  ];
    r.y = aL[o+1]*v.y + cL[o+1];
    r.z = aL[o+2]*v.z + cL[o+2];
    r.w = aL[o+3]*v.w + cL[o+3];
    *reinterpret_cast<float4*>(out + (size_t)i4*4) = r;
  }
}

extern "C" void kernel_launch(void* const* d_in, const int* in_sizes, int n_in,
                              void* d_out, int out_size, void* d_ws, size_t ws_size,
                              hipStream_t stream) {
  const float* ms    = (const float*)d_in[0];
  const int*   gidx  = (const int*)  d_in[1];
  const float* W1    = (const float*)d_in[2];
  const float* b1    = (const float*)d_in[3];
  const float* g1    = (const float*)d_in[4];
  const float* beta1 = (const float*)d_in[5];
  const float* W2    = (const float*)d_in[6];
  const float* b2    = (const float*)d_in[7];
  const float* g2    = (const float*)d_in[8];
  const float* beta2 = (const float*)d_in[9];
  const float* W3    = (const float*)d_in[10];
  const float* b3    = (const float*)d_in[11];
  const float* g3    = (const float*)d_in[12];
  const float* beta3 = (const float*)d_in[13];
  const float* Wr    = (const float*)d_in[14];
  const float* br    = (const float*)d_in[15];
  const float* gr    = (const float*)d_in[16];
  const float* betar = (const float*)d_in[17];
  float* out = (float*)d_out;

  char* w = (char*)d_ws;
  size_t off = 0;
  auto take = [&](size_t bytes)->char*{
    char* p = w + off;
    off = (off + bytes + 255) & ~(size_t)255;
    return p;
  };
  h16*   msT    = (h16*)  take((size_t)6000*BATCH*2);
  h16*   H2     = (h16*)  take((size_t)64*BATCH*24*2);
  h16*   H3     = (h16*)  take((size_t)BATCH*256*2);
  float* Hr     = (float*)take((size_t)BATCH*64*4);
  float* part1  = (float*)take((size_t)10240*2*16*4);
  float* part2  = (float*)take((size_t)1536*2*32*4);
  float* part3  = (float*)take((size_t)256*2*32*4);
  float* partR  = (float*)take((size_t)64*2*64*4);
  float* W2f    = (float*)take((size_t)64*24*160*4);
  float* b2f    = (float*)take((size_t)64*24*4);
  float* W3f    = (float*)take((size_t)8*32*192*4);
  float* b3f    = (float*)take((size_t)8*32*4);
  float* Wrf    = (float*)take((size_t)64*256*4);
  float* brf    = (float*)take((size_t)64*4);
  if (off > ws_size) return;

  k_transpose<<<dim3(94,64), 256, 0, stream>>>(ms, msT);
  k_statsA<<<dim3(16,512), 64, 0, stream>>>(msT, gidx, W1, b1, part1);
  k_fold<160,24,16,true><<<64, 256, 0, stream>>>(W2, b2, g1, beta1, part1, W2f, b2f);
  k_passB<<<dim3(32,64), 64, 0, stream>>>(msT, gidx, W1, b1, W2f, b2f, H2, part2);
  k_fold<192,32,32,false><<<8, 256, 0, stream>>>(W3, b3, g2, beta2, part2, W3f, b3f);
  k_passC<<<dim3(32,8), 256, 0, stream>>>(H2, W3f, b3f, H3, part3);
  k_fold<256,64,32,false><<<1, 256, 0, stream>>>(Wr, br, g3, beta3, part3, Wrf, brf);
  k_passD<<<64, 256, 0, stream>>>(H3, Wrf, brf, Hr, partR);
  k_final<<<64, 256, 0, stream>>>(Hr, partR, gr, betar, out);
}

// Round 3
// 248.876 us; speedup vs baseline: 1.5607x; 1.1655x over previous
//
#include <hip/hip_runtime.h>
#include <hip/hip_fp16.h>

#define BATCH 4096
#define EPS 1e-5f

typedef __half h16;

union H8 { float4 f4; h16 h[8]; };
union H2U { float f; __half2 h2; unsigned int u; };

__device__ __forceinline__ float tanh_fast(float x){
  float e = __expf(2.0f*x);
  return 1.0f - 2.0f*__builtin_amdgcn_rcpf(e + 1.0f);
}

__device__ __forceinline__ float wred(float v){
  #pragma unroll
  for (int off=32; off; off>>=1) v += __shfl_xor(v, off);
  return v;
}

// ---------------- transpose: ms[4096][6000] f32 -> msT[6000][4096] f16 ----------------
__global__ __launch_bounds__(256) void k_transpose(const float* __restrict__ ms, h16* __restrict__ msT){
  __shared__ float tile[64][65];
  int tc = blockIdx.x * 64;
  int tb = blockIdx.y * 64;
  int tx = threadIdx.x & 63;
  int ty = threadIdx.x >> 6;
  #pragma unroll
  for (int k=0;k<16;++k){
    int r = ty + k*4;
    int c = tc + tx;
    if (c < 6000) tile[r][tx] = ms[(size_t)(tb + r)*6000 + c];
  }
  __syncthreads();
  #pragma unroll
  for (int k=0;k<16;++k){
    int r = ty + k*4;
    int c = tc + r;
    if (c < 6000) msT[(size_t)c*BATCH + tb + tx] = __float2half(tile[tx][r]);
  }
}

// ---------------- pass A: level-1 stats only ----------------
// grid (32 bc, 512 s), block 64; thread handles 2 batch elems
__global__ __launch_bounds__(64) void k_statsA(const h16* __restrict__ msT, const int* __restrict__ gidx,
    const float* __restrict__ W1, const float* __restrict__ b1, float* __restrict__ part1){
  const int s = blockIdx.y;
  const int bc = blockIdx.x;           // 32
  const int lane = threadIdx.x;
  const int b0 = bc*128 + lane*2;
  const float* Wp = W1 + s*320;
  float acc[20][2];
  #pragma unroll
  for (int o=0;o<20;++o){ float bv = b1[s*20+o]; acc[o][0]=bv; acc[o][1]=bv; }
  #pragma unroll 4
  for (int g=0; g<16; ++g){
    const int row = gidx[s*16+g]*BATCH;
    H2U u; u.f = *reinterpret_cast<const float*>(msT + row + b0);
    float x0 = __half2float(u.h2.x), x1 = __half2float(u.h2.y);
    #pragma unroll
    for (int o=0;o<20;++o){
      float wv = Wp[o*16+g];
      acc[o][0]=fmaf(x0,wv,acc[o][0]);
      acc[o][1]=fmaf(x1,wv,acc[o][1]);
    }
  }
  #pragma unroll
  for (int o=0;o<20;++o){
    float h0=tanh_fast(acc[o][0]), h1=tanh_fast(acc[o][1]);
    float S = wred(h0+h1);
    float Q = wred(h0*h0+h1*h1);
    if (lane==0){
      part1[((s*20+o)*2  )*32 + bc] = S;
      part1[((s*20+o)*2+1)*32 + bc] = Q;
    }
  }
}

// ---------------- fold level-1 BN into W2 (transposed [i][j] layout) ----------------
__global__ __launch_bounds__(256) void k_fold2(const float* __restrict__ W, const float* __restrict__ bb,
    const float* __restrict__ g, const float* __restrict__ beta,
    const float* __restrict__ part, float* __restrict__ Wf, float* __restrict__ bf){
  const int p = blockIdx.x;
  const int tid = threadIdx.x;
  __shared__ float aL[160], cL[160];
  for (int t = tid; t < 160; t += 256){
    int ch = p*160 + t;
    float S=0.f, Q=0.f;
    for (int bc=0; bc<32; ++bc){ S += part[(ch*2)*32 + bc]; Q += part[(ch*2+1)*32 + bc]; }
    float mu  = S * (1.0f/BATCH);
    float var = Q * (1.0f/BATCH) - mu*mu;
    float a = g[ch] * rsqrtf(var + EPS);
    aL[t] = a;
    cL[t] = beta[ch] - a*mu;
  }
  __syncthreads();
  const int NW = 160*24;
  for (int e = tid; e < NW; e += 256){
    int j = e % 24, i = e / 24;
    Wf[p*NW + e] = W[p*NW + j*160 + i] * aL[i];
  }
  if (tid < 24){
    float sv = bb[p*24 + tid];
    for (int i=0;i<160;++i) sv = fmaf(W[p*NW + tid*160 + i], cL[i], sv);
    bf[p*24 + tid] = sv;
  }
}

// ---------------- pass B: recompute h1 + folded level-2 -> H2[p][b][24] + stats ----------------
// grid (64 bc, 64 p), block 64; 1 batch elem per thread
__global__ __launch_bounds__(64) void k_passB(const h16* __restrict__ msT, const int* __restrict__ gidx,
    const float* __restrict__ W1, const float* __restrict__ b1,
    const float* __restrict__ W2f, const float* __restrict__ b2f,
    h16* __restrict__ H2, float* __restrict__ part2){
  const int p = blockIdx.y;
  const int bc = blockIdx.x;           // 64
  const int lane = threadIdx.x;
  const int b = bc*64 + lane;
  float acc[24];
  #pragma unroll
  for (int j=0;j<24;++j) acc[j] = b2f[p*24+j];
  for (int c2=0;c2<8;++c2){
    const int s = p*8 + c2;
    const float* Wp = W1 + s*320;
    const float* bp = b1 + s*20;
    float x[16];
    #pragma unroll
    for (int g=0; g<16; ++g){
      const int row = gidx[s*16+g]*BATCH;
      x[g] = __half2float(msT[row + b]);
    }
    const float* w2 = W2f + p*3840 + c2*480;   // [i][j] layout
    #pragma unroll 4
    for (int o=0;o<20;++o){
      float h = bp[o];
      #pragma unroll
      for (int g=0; g<16; ++g) h = fmaf(x[g], Wp[o*16+g], h);
      h = tanh_fast(h);
      const float* wj = w2 + o*24;
      #pragma unroll
      for (int j=0;j<24;++j) acc[j] = fmaf(h, wj[j], acc[j]);
    }
  }
  #pragma unroll
  for (int j=0;j<24;++j) acc[j] = tanh_fast(acc[j]);
  // store 24 halves (48B per lane, 16B-aligned)
  {
    h16* dst = H2 + ((size_t)p*BATCH + b)*24;
    H8 u;
    #pragma unroll
    for (int t=0;t<3;++t){
      #pragma unroll
      for (int j=0;j<8;++j) u.h[j] = __float2half(acc[t*8+j]);
      *reinterpret_cast<float4*>(dst + t*8) = u.f4;
    }
  }
  #pragma unroll
  for (int j=0;j<24;++j){
    float S = wred(acc[j]);
    float Q = wred(acc[j]*acc[j]);
    if (lane==0){
      part2[((p*24+j)*2  )*64 + bc] = S;
      part2[((p*24+j)*2+1)*64 + bc] = Q;
    }
  }
}

// ---------------- pass C: inline-BN(level2) + level-3 -> H3[b][256] + stats ----------------
// grid (64 bc, 8 q), block 512 (8 waves x 4 outputs); 1 elem per thread
__global__ __launch_bounds__(512) void k_passC(const h16* __restrict__ H2, const float* __restrict__ part2,
    const float* __restrict__ g2, const float* __restrict__ beta2,
    const float* __restrict__ W3, const float* __restrict__ b3,
    h16* __restrict__ H3, float* __restrict__ part3){
  const int q = blockIdx.y;
  const int bc = blockIdx.x;           // 64
  const int tid = threadIdx.x;
  const int wv = tid >> 6;
  const int lane = tid & 63;
  __shared__ float aL[192], cL[192];
  for (int t = tid; t < 192; t += 512){
    int ch = q*192 + t;
    float S=0.f, Q=0.f;
    for (int c=0;c<64;++c){ S += part2[(ch*2)*64 + c]; Q += part2[(ch*2+1)*64 + c]; }
    float mu  = S * (1.0f/BATCH);
    float var = Q * (1.0f/BATCH) - mu*mu;
    float a = g2[ch] * rsqrtf(var + EPS);
    aL[t] = a; cL[t] = beta2[ch] - a*mu;
  }
  __syncthreads();
  const int b = bc*64 + lane;
  const int jb = wv*4;
  float acc[4];
  #pragma unroll
  for (int j=0;j<4;++j) acc[j] = b3[q*32 + jb + j];
  for (int c2=0;c2<8;++c2){
    const h16* src = H2 + ((size_t)(q*8+c2)*BATCH + b)*24;
    float xn[24];
    #pragma unroll
    for (int t=0;t<3;++t){
      H8 u; u.f4 = *reinterpret_cast<const float4*>(src + t*8);
      #pragma unroll
      for (int i=0;i<8;++i){
        int ci = c2*24 + t*8 + i;
        xn[t*8+i] = fmaf(aL[ci], __half2float(u.h[i]), cL[ci]);
      }
    }
    #pragma unroll
    for (int j=0;j<4;++j){
      const float* wr = W3 + q*6144 + (jb+j)*192 + c2*24;
      #pragma unroll
      for (int i=0;i<24;++i) acc[j] = fmaf(xn[i], wr[i], acc[j]);
    }
  }
  #pragma unroll
  for (int j=0;j<4;++j) acc[j] = tanh_fast(acc[j]);
  {
    h16* dst = H3 + (size_t)b*256 + q*32 + jb;
    H2U u0,u1;
    u0.h2 = __halves2half2(__float2half(acc[0]), __float2half(acc[1]));
    u1.h2 = __halves2half2(__float2half(acc[2]), __float2half(acc[3]));
    float2 v; v.x = u0.f; v.y = u1.f;
    *reinterpret_cast<float2*>(dst) = v;
  }
  #pragma unroll
  for (int j=0;j<4;++j){
    float S = wred(acc[j]);
    float Q = wred(acc[j]*acc[j]);
    if (lane==0){
      part3[((q*32+jb+j)*2  )*64 + bc] = S;
      part3[((q*32+jb+j)*2+1)*64 + bc] = Q;
    }
  }
}

// ---------------- pass D: inline-BN(level3) + root -> Hr f32 [b][64] + stats ----------------
// grid (64 bc, 8 jg), block 64; 1 elem per thread, 8 outputs
__global__ __launch_bounds__(64) void k_passD(const h16* __restrict__ H3, const float* __restrict__ part3,
    const float* __restrict__ g3, const float* __restrict__ beta3,
    const float* __restrict__ Wr, const float* __restrict__ br,
    float* __restrict__ Hr, float* __restrict__ partR){
  const int bc = blockIdx.x;           // 64
  const int jb = blockIdx.y * 8;       // 8 groups
  const int lane = threadIdx.x;
  __shared__ float aL[256], cL[256];
  for (int t = lane; t < 256; t += 64){
    float S=0.f, Q=0.f;
    for (int c=0;c<64;++c){ S += part3[(t*2)*64 + c]; Q += part3[(t*2+1)*64 + c]; }
    float mu  = S * (1.0f/BATCH);
    float var = Q * (1.0f/BATCH) - mu*mu;
    float a = g3[t] * rsqrtf(var + EPS);
    aL[t] = a; cL[t] = beta3[t] - a*mu;
  }
  __syncthreads();
  const int b = bc*64 + lane;
  float acc[8];
  #pragma unroll
  for (int j=0;j<8;++j) acc[j] = br[jb+j];
  const h16* src = H3 + (size_t)b*256;
  #pragma unroll 4
  for (int sl=0; sl<32; ++sl){
    H8 u; u.f4 = *reinterpret_cast<const float4*>(src + sl*8);
    float xn[8];
    #pragma unroll
    for (int i=0;i<8;++i){
      int ci = sl*8+i;
      xn[i] = fmaf(aL[ci], __half2float(u.h[i]), cL[ci]);
    }
    #pragma unroll
    for (int j=0;j<8;++j){
      const float* wr = Wr + (jb+j)*256 + sl*8;
      #pragma unroll
      for (int i=0;i<8;++i) acc[j] = fmaf(xn[i], wr[i], acc[j]);
    }
  }
  #pragma unroll
  for (int j=0;j<8;++j) acc[j] = tanh_fast(acc[j]);
  #pragma unroll
  for (int t=0;t<2;++t){
    float4 v = make_float4(acc[t*4],acc[t*4+1],acc[t*4+2],acc[t*4+3]);
    *reinterpret_cast<float4*>(Hr + (size_t)b*64 + jb + t*4) = v;
  }
  #pragma unroll
  for (int j=0;j<8;++j){
    float S = wred(acc[j]);
    float Q = wred(acc[j]*acc[j]);
    if (lane==0){
      partR[((jb+j)*2  )*64 + bc] = S;
      partR[((jb+j)*2+1)*64 + bc] = Q;
    }
  }
}

// ---------------- final BN on root output ----------------
__global__ __launch_bounds__(256) void k_final(const float* __restrict__ Hr, const float* __restrict__ partR,
    const float* __restrict__ gr, const float* __restrict__ betar, float* __restrict__ out){
  __shared__ float aL[64], cL[64];
  const int tid = threadIdx.x;
  if (tid < 64){
    float S=0.f, Q=0.f;
    for (int bc=0; bc<64; ++bc){ S += partR[(tid*2)*64 + bc]; Q += partR[(tid*2+1)*64 + bc]; }
    float mu  = S * (1.0f/BATCH);
    float var = Q * (1.0f/BATCH) - mu*mu;
    float a = gr[tid] * rsqrtf(var + EPS);
    aL[tid] = a; cL[tid] = betar[tid] - a*mu;
  }
  __syncthreads();
  const int i4 = blockIdx.x*256 + tid;       // 65536 float4s
  float4 v = *reinterpret_cast<const float4*>(Hr + (size_t)i4*4);
  int o = (i4*4)&63;
  float4 r;
  r.x = aL[o  ]*v.x + cL[o  ];
  r.y = aL[o+1]*v.y + cL[o+1];
  r.z = aL[o+2]*v.z + cL[o+2];
  r.w = aL[o+3]*v.w + cL[o+3];
  *reinterpret_cast<float4*>(out + (size_t)i4*4) = r;
}

extern "C" void kernel_launch(void* const* d_in, const int* in_sizes, int n_in,
                              void* d_out, int out_size, void* d_ws, size_t ws_size,
                              hipStream_t stream) {
  const float* ms    = (const float*)d_in[0];
  const int*   gidx  = (const int*)  d_in[1];
  const float* W1    = (const float*)d_in[2];
  const float* b1    = (const float*)d_in[3];
  const float* g1    = (const float*)d_in[4];
  const float* beta1 = (const float*)d_in[5];
  const float* W2    = (const float*)d_in[6];
  const float* b2    = (const float*)d_in[7];
  const float* g2    = (const float*)d_in[8];
  const float* beta2 = (const float*)d_in[9];
  const float* W3    = (const float*)d_in[10];
  const float* b3    = (const float*)d_in[11];
  const float* g3    = (const float*)d_in[12];
  const float* beta3 = (const float*)d_in[13];
  const float* Wr    = (const float*)d_in[14];
  const float* br    = (const float*)d_in[15];
  const float* gr    = (const float*)d_in[16];
  const float* betar = (const float*)d_in[17];
  float* out = (float*)d_out;

  char* w = (char*)d_ws;
  size_t off = 0;
  auto take = [&](size_t bytes)->char*{
    char* p = w + off;
    off = (off + bytes + 255) & ~(size_t)255;
    return p;
  };
  h16*   msT    = (h16*)  take((size_t)6000*BATCH*2);
  h16*   H2     = (h16*)  take((size_t)64*BATCH*24*2);
  h16*   H3     = (h16*)  take((size_t)BATCH*256*2);
  float* Hr     = (float*)take((size_t)BATCH*64*4);
  float* part1  = (float*)take((size_t)10240*2*32*4);
  float* part2  = (float*)take((size_t)1536*2*64*4);
  float* part3  = (float*)take((size_t)256*2*64*4);
  float* partR  = (float*)take((size_t)64*2*64*4);
  float* W2f    = (float*)take((size_t)64*24*160*4);
  float* b2f    = (float*)take((size_t)64*24*4);
  if (off > ws_size) return;

  k_transpose<<<dim3(94,64), 256, 0, stream>>>(ms, msT);
  k_statsA<<<dim3(32,512), 64, 0, stream>>>(msT, gidx, W1, b1, part1);
  k_fold2<<<64, 256, 0, stream>>>(W2, b2, g1, beta1, part1, W2f, b2f);
  k_passB<<<dim3(64,64), 64, 0, stream>>>(msT, gidx, W1, b1, W2f, b2f, H2, part2);
  k_passC<<<dim3(64,8), 512, 0, stream>>>(H2, part2, g2, beta2, W3, b3, H3, part3);
  k_passD<<<dim3(64,8), 64, 0, stream>>>(H3, part3, g3, beta3, Wr, br, Hr, partR);
  k_final<<<256, 256, 0, stream>>>(Hr, partR, gr, betar, out);
}